// Round 2
// 377.566 us; speedup vs baseline: 1.0470x; 1.0470x over previous
//
#include <hip/hip_runtime.h>

#define EMBED   768
#define EMBED4  192
#define POOL    60
#define BATCH   128
#define SEQ     512
#define TOPK    5
#define LEN     5
#define OUTROWS 537   // TOPK*LEN + SEQ = 25 + 512
#define NSLICE  16    // slices per batch in the streaming kernel

// ---- output layout (float offsets, concatenated in reference return order) ----
#define SZ_PE   (128L*537L*768L)          // 52,789,248
#define OFF_RS  (SZ_PE)                   // reduce_sim scalar
#define OFF_IDX (OFF_RS + 1)              // 128*5 = 640
#define OFF_SIM (OFF_IDX + 640)           // 128*60 = 7680
#define OFF_SK  (OFF_SIM + 7680)          // 128*5*768 = 491,520  (NOT 16B-aligned: OFF_SK%4==1)

// ---- workspace layout (float offsets) ----
#define WS_PARTIAL 0                      // 128*16*768 = 1,572,864
#define WS_KEYBALL 1572864                // 60*768     =    46,080
#define WS_KEYY2   1618944                // 60
#define WS_SEL     1619008                // 128*5 ints

#define MAX_NORM_F 0.996f                 // 1.0 - 4e-3

// native vector type for nontemporal builtins (HIP float4 is a struct and is rejected)
typedef float fx4 __attribute__((ext_vector_type(4)));

__device__ __forceinline__ float block_reduce_256(float v, float* red) {
    int tid = threadIdx.x;
    #pragma unroll
    for (int m = 32; m >= 1; m >>= 1) v += __shfl_xor(v, m, 64);
    if ((tid & 63) == 0) red[tid >> 6] = v;
    __syncthreads();
    float total = red[0] + red[1] + red[2] + red[3];
    __syncthreads();   // guard before red[] reuse
    return total;
}

// Fused: stream x_embed -> output rows [25..536] while accumulating per-batch partial sums.
// grid (NSLICE, 128 batches), block 192 (one float4 column per thread), 32 rows per block.
// 8-deep load batching: 8 loads in flight per thread before the dependent store pass.
// NT hints on the 402 MB stream: written/read once, never reused -> don't occupy L2/L3.
__global__ __launch_bounds__(192) void mean_partial_copy(
        const float* __restrict__ x, float* __restrict__ out, float* __restrict__ partial) {
    const int slice = blockIdx.x, b = blockIdx.y, tid = threadIdx.x;
    const fx4* __restrict__ x4 = (const fx4*)x;
    fx4* __restrict__ out4 = (fx4*)out;
    fx4* __restrict__ p4 = (fx4*)partial;

    if (slice == 0 && b == 0 && tid == 0) out[OFF_RS] = 0.0f;  // zero reduce_sim (pre-topk, stream-ordered)

    fx4 acc = (fx4)(0.f);
    const int rows = SEQ / NSLICE;  // 32
    const long ibase = ((long)b * SEQ + slice * rows) * EMBED4 + tid;
    const long obase = ((long)b * OUTROWS + 25 + slice * rows) * EMBED4 + tid;
    #pragma unroll
    for (int s0 = 0; s0 < rows; s0 += 8) {
        fx4 v[8];
        #pragma unroll
        for (int i = 0; i < 8; ++i)
            v[i] = __builtin_nontemporal_load(&x4[ibase + (long)(s0 + i) * EMBED4]);
        #pragma unroll
        for (int i = 0; i < 8; ++i) {
            // accumulate in the same s = 0..31 order as before (bitwise-identical mean)
            acc += v[i];
            __builtin_nontemporal_store(v[i], &out4[obase + (long)(s0 + i) * EMBED4]);
        }
    }
    p4[(long)(b * NSLICE + slice) * EMBED4 + tid] = acc;
}

// map_to_ball(prompt_key) -> keyball, keyy2.  grid 60, block 256 (3 elems/thread)
__global__ __launch_bounds__(256) void keyball_kernel(
        const float* __restrict__ pkey, float* __restrict__ keyball, float* __restrict__ keyy2) {
    __shared__ float red[4];
    const int p = blockIdx.x, tid = threadIdx.x;
    float v[3];
    float ss = 0.f;
    #pragma unroll
    for (int j = 0; j < 3; ++j) { v[j] = pkey[p * EMBED + tid + 256 * j]; ss += v[j] * v[j]; }
    ss = block_reduce_256(ss, red);
    const float scale1 = rsqrtf(fmaxf(ss, 1e-12f)) * 0.1f;   // l2_normalize * MAP_SCALE
    float su = 0.f;
    #pragma unroll
    for (int j = 0; j < 3; ++j) { v[j] *= scale1; su += v[j] * v[j]; }
    su = block_reduce_256(su, red);
    const float n = sqrtf(fmaxf(su, 1e-15f));
    const float f = tanhf(n) / n;                             // expmap0
    float sb = 0.f;
    #pragma unroll
    for (int j = 0; j < 3; ++j) { v[j] *= f; sb += v[j] * v[j]; }
    sb = block_reduce_256(sb, red);
    const float n2 = sqrtf(fmaxf(sb, 1e-15f));
    const float g = (n2 > MAX_NORM_F) ? (MAX_NORM_F / n2) : 1.0f;  // proju0
    #pragma unroll
    for (int j = 0; j < 3; ++j) keyball[p * EMBED + tid + 256 * j] = v[j] * g;
    if (tid == 0) keyy2[p] = sb * g * g;
}

// Per-batch: finalize mean, q_ball, distances, similarity, top-5, idx, reduce_sim.
// Gather work moved to gather_kernel (this kernel is latency-bound at 128 blocks).
// grid 128, block 256
__global__ __launch_bounds__(256) void topk_core(
        const float* __restrict__ partial, const float* __restrict__ keyball,
        const float* __restrict__ keyy2, float* __restrict__ out, int* __restrict__ selw) {
    __shared__ float red[4];
    __shared__ float q[EMBED];
    __shared__ float xy[POOL];
    __shared__ float dist[POOL];
    const int b = blockIdx.x, tid = threadIdx.x;

    // ---- finalize mean: sum NSLICE partials per column (in slice order), /512 ----
    float v[3];
    {
        const float inv = 1.0f / (float)SEQ;
        #pragma unroll
        for (int j = 0; j < 3; ++j) {
            const int col = tid + 256 * j;
            float s = 0.f;
            #pragma unroll
            for (int sl = 0; sl < NSLICE; ++sl)
                s += partial[(long)(b * NSLICE + sl) * EMBED + col];
            v[j] = s * inv;
        }
    }

    // ---- q_ball = map_to_ball(x_mean[b]) ----
    float ss = 0.f;
    #pragma unroll
    for (int j = 0; j < 3; ++j) ss += v[j] * v[j];
    ss = block_reduce_256(ss, red);
    const float scale1 = rsqrtf(fmaxf(ss, 1e-12f)) * 0.1f;
    float su = 0.f;
    #pragma unroll
    for (int j = 0; j < 3; ++j) { v[j] *= scale1; su += v[j] * v[j]; }
    su = block_reduce_256(su, red);
    const float n = sqrtf(fmaxf(su, 1e-15f));
    const float f = tanhf(n) / n;
    float sb = 0.f;
    #pragma unroll
    for (int j = 0; j < 3; ++j) { v[j] *= f; sb += v[j] * v[j]; }
    sb = block_reduce_256(sb, red);
    const float n2 = sqrtf(fmaxf(sb, 1e-15f));
    const float g = (n2 > MAX_NORM_F) ? (MAX_NORM_F / n2) : 1.0f;
    const float x2 = sb * g * g;
    #pragma unroll
    for (int j = 0; j < 3; ++j) q[tid + 256 * j] = v[j] * g;
    __syncthreads();

    // ---- xy[p] = <q, key_ball[p]> : each wave handles 15 keys ----
    const int wave = tid >> 6, lane = tid & 63;
    for (int p = wave; p < POOL; p += 4) {
        const float* __restrict__ kb = keyball + p * EMBED;
        float acc = 0.f;
        #pragma unroll
        for (int d = 0; d < EMBED; d += 64) acc += q[d + lane] * kb[d + lane];
        #pragma unroll
        for (int m = 32; m >= 1; m >>= 1) acc += __shfl_xor(acc, m, 64);
        if (lane == 0) xy[p] = acc;
    }
    __syncthreads();

    // ---- distances (scalar-only mobius math) ----
    if (tid < POOL) {
        const float s = xy[tid];
        const float y2 = keyy2[tid];
        const float A = 1.0f - 2.0f * s + y2;       // coeff on -x in num
        const float B = 1.0f - x2;                  // coeff on  y in num
        const float num2 = A * A * x2 + B * B * y2 - 2.0f * A * B * s;
        const float den = fmaxf(1.0f - 2.0f * s + x2 * y2, 1e-15f);
        float nn = sqrtf(fmaxf(num2 / (den * den), 1e-15f));
        nn = fminf(fmaxf(nn, 0.0f), 1.0f - 1e-7f);
        const float dd = logf((1.0f + nn) / (1.0f - nn));   // 2*artanh(nn)
        dist[tid] = dd;
        out[OFF_SIM + (long)b * POOL + tid] = -dd;
    }
    __syncthreads();

    // ---- top-5 (largest similarity = smallest dist; ties -> lowest index), sort, reduce_sim ----
    if (tid == 0) {
        int sel[TOPK];
        unsigned long long mask = 0ULL;
        for (int k = 0; k < TOPK; ++k) {
            int best = 0; float bd = 1e30f;
            for (int p = 0; p < POOL; ++p) {
                if (mask & (1ULL << p)) continue;
                if (dist[p] < bd) { bd = dist[p]; best = p; }   // strict < keeps lowest index on tie
            }
            mask |= 1ULL << best;
            sel[k] = best;
        }
        #pragma unroll
        for (int i = 0; i < TOPK; ++i)
            for (int j2 = i + 1; j2 < TOPK; ++j2)
                if (sel[j2] < sel[i]) { int t = sel[i]; sel[i] = sel[j2]; sel[j2] = t; }
        float sum = 0.f;
        for (int k = 0; k < TOPK; ++k) {
            sum += dist[sel[k]];
            out[OFF_IDX + (long)b * TOPK + k] = (float)sel[k];
            selw[b * TOPK + k] = sel[k];
        }
        atomicAdd(&out[OFF_RS], sum * (1.0f / 128.0f));
    }
}

// Gather: one 768-float row per block.
// grid (30, 128): r in [0,25) -> prompt row copy (float4); r in [25,30) -> selected_key row (scalar,
// OFF_SK is not 16B-aligned).  block 192.
__global__ __launch_bounds__(192) void gather_kernel(
        const float* __restrict__ prompt, const float* __restrict__ keyball,
        const int* __restrict__ selw, float* __restrict__ out) {
    const int r = blockIdx.x, b = blockIdx.y, tid = threadIdx.x;
    if (r < TOPK * LEN) {
        const int k = r / LEN, l = r - k * LEN;
        const int pi = selw[b * TOPK + k];          // block-uniform -> scalar load
        const float4* __restrict__ src = (const float4*)prompt + ((long)pi * LEN + l) * EMBED4;
        float4* __restrict__ dst = (float4*)out + ((long)b * OUTROWS + r) * EMBED4;
        dst[tid] = src[tid];
    } else {
        const int k = r - TOPK * LEN;
        const int pi = selw[b * TOPK + k];
        const float* __restrict__ src = keyball + (long)pi * EMBED;
        float* __restrict__ dst = out + OFF_SK + ((long)b * TOPK + k) * EMBED;
        #pragma unroll
        for (int j = 0; j < 4; ++j) dst[tid + 192 * j] = src[tid + 192 * j];
    }
}

extern "C" void kernel_launch(void* const* d_in, const int* in_sizes, int n_in,
                              void* d_out, int out_size, void* d_ws, size_t ws_size,
                              hipStream_t stream) {
    const float* x      = (const float*)d_in[0];   // [128,512,768]
    const float* prompt = (const float*)d_in[1];   // [60,5,768]
    const float* pkey   = (const float*)d_in[2];   // [60,768]
    float* out = (float*)d_out;
    float* ws  = (float*)d_ws;

    float* partial = ws + WS_PARTIAL;
    float* keyball = ws + WS_KEYBALL;
    float* keyy2   = ws + WS_KEYY2;
    int*   selw    = (int*)(ws + WS_SEL);

    hipLaunchKernelGGL(mean_partial_copy, dim3(NSLICE, 128), dim3(192), 0, stream, x, out, partial);
    hipLaunchKernelGGL(keyball_kernel,    dim3(60),          dim3(256), 0, stream, pkey, keyball, keyy2);
    hipLaunchKernelGGL(topk_core,         dim3(128),         dim3(256), 0, stream,
                       partial, keyball, keyy2, out, selw);
    hipLaunchKernelGGL(gather_kernel,     dim3(30, 128),     dim3(192), 0, stream,
                       prompt, keyball, selw, out);
}

// Round 3
// 363.067 us; speedup vs baseline: 1.0888x; 1.0399x over previous
//
#include <hip/hip_runtime.h>

#define EMBED   768
#define EMBED4  192
#define POOL    60
#define BATCH   128
#define SEQ     512
#define TOPK    5
#define LEN     5
#define OUTROWS 537   // TOPK*LEN + SEQ = 25 + 512
#define NSLICE  16    // slices per batch in the streaming kernel

// ---- output layout (float offsets, concatenated in reference return order) ----
#define SZ_PE   (128L*537L*768L)          // 52,789,248
#define OFF_RS  (SZ_PE)                   // reduce_sim scalar
#define OFF_IDX (OFF_RS + 1)              // 128*5 = 640
#define OFF_SIM (OFF_IDX + 640)           // 128*60 = 7680
#define OFF_SK  (OFF_SIM + 7680)          // 128*5*768 = 491,520  (NOT 16B-aligned: OFF_SK%4==1)

// ---- workspace layout (float offsets) ----
#define WS_PARTIAL 0                      // 128*16*768 = 1,572,864
#define WS_KEYBALL 1572864                // 60*768     =    46,080
#define WS_KEYY2   1618944                // 60
#define WS_SEL     1619008                // 128*5 ints

#define MAX_NORM_F 0.996f                 // 1.0 - 4e-3

// native vector type for nontemporal builtins (HIP float4 is a struct and is rejected)
typedef float fx4 __attribute__((ext_vector_type(4)));

__device__ __forceinline__ float block_reduce_256(float v, float* red) {
    int tid = threadIdx.x;
    #pragma unroll
    for (int m = 32; m >= 1; m >>= 1) v += __shfl_xor(v, m, 64);
    if ((tid & 63) == 0) red[tid >> 6] = v;
    __syncthreads();
    float total = red[0] + red[1] + red[2] + red[3];
    __syncthreads();   // guard before red[] reuse
    return total;
}

// Fused: stream x_embed -> output rows [25..536] while accumulating per-batch partial sums.
// grid (NSLICE, 128 batches), block 192 (one float4 column per thread), 32 rows per block.
// 16-deep load batching: 16 loads in flight per thread before the dependent store pass
// (64 data VGPRs; ~90 total -> occupancy unaffected).  NT hints: stream is written/read once.
__global__ __launch_bounds__(192) void mean_partial_copy(
        const float* __restrict__ x, float* __restrict__ out, float* __restrict__ partial) {
    const int slice = blockIdx.x, b = blockIdx.y, tid = threadIdx.x;
    const fx4* __restrict__ x4 = (const fx4*)x;
    fx4* __restrict__ out4 = (fx4*)out;
    fx4* __restrict__ p4 = (fx4*)partial;

    if (slice == 0 && b == 0 && tid == 0) out[OFF_RS] = 0.0f;  // zero reduce_sim (pre-topk, stream-ordered)

    fx4 acc = (fx4)(0.f);
    const int rows = SEQ / NSLICE;  // 32
    const long ibase = ((long)b * SEQ + slice * rows) * EMBED4 + tid;
    const long obase = ((long)b * OUTROWS + 25 + slice * rows) * EMBED4 + tid;
    #pragma unroll
    for (int s0 = 0; s0 < rows; s0 += 16) {
        fx4 v[16];
        #pragma unroll
        for (int i = 0; i < 16; ++i)
            v[i] = __builtin_nontemporal_load(&x4[ibase + (long)(s0 + i) * EMBED4]);
        #pragma unroll
        for (int i = 0; i < 16; ++i) {
            // accumulate in the same s = 0..31 order as before (bitwise-identical mean)
            acc += v[i];
            __builtin_nontemporal_store(v[i], &out4[obase + (long)(s0 + i) * EMBED4]);
        }
    }
    p4[(long)(b * NSLICE + slice) * EMBED4 + tid] = acc;
}

// map_to_ball(prompt_key) -> keyball, keyy2.  grid 60, block 256 (3 elems/thread)
__global__ __launch_bounds__(256) void keyball_kernel(
        const float* __restrict__ pkey, float* __restrict__ keyball, float* __restrict__ keyy2) {
    __shared__ float red[4];
    const int p = blockIdx.x, tid = threadIdx.x;
    float v[3];
    float ss = 0.f;
    #pragma unroll
    for (int j = 0; j < 3; ++j) { v[j] = pkey[p * EMBED + tid + 256 * j]; ss += v[j] * v[j]; }
    ss = block_reduce_256(ss, red);
    const float scale1 = rsqrtf(fmaxf(ss, 1e-12f)) * 0.1f;   // l2_normalize * MAP_SCALE
    float su = 0.f;
    #pragma unroll
    for (int j = 0; j < 3; ++j) { v[j] *= scale1; su += v[j] * v[j]; }
    su = block_reduce_256(su, red);
    const float n = sqrtf(fmaxf(su, 1e-15f));
    const float f = tanhf(n) / n;                             // expmap0
    float sb = 0.f;
    #pragma unroll
    for (int j = 0; j < 3; ++j) { v[j] *= f; sb += v[j] * v[j]; }
    sb = block_reduce_256(sb, red);
    const float n2 = sqrtf(fmaxf(sb, 1e-15f));
    const float g = (n2 > MAX_NORM_F) ? (MAX_NORM_F / n2) : 1.0f;  // proju0
    #pragma unroll
    for (int j = 0; j < 3; ++j) keyball[p * EMBED + tid + 256 * j] = v[j] * g;
    if (tid == 0) keyy2[p] = sb * g * g;
}

// Per-batch: finalize mean, q_ball, distances, similarity, top-5, idx, reduce_sim.
// grid 128, block 256.  Latency-oriented: dual-key interleave in the xy phase,
// wave-parallel top-5 with exact (dist,index) tie-break semantics.
__global__ __launch_bounds__(256) void topk_core(
        const float* __restrict__ partial, const float* __restrict__ keyball,
        const float* __restrict__ keyy2, float* __restrict__ out, int* __restrict__ selw) {
    __shared__ float red[4];
    __shared__ float q[EMBED];
    __shared__ float xy[POOL];
    __shared__ float dist[POOL];
    const int b = blockIdx.x, tid = threadIdx.x;

    // ---- finalize mean: sum NSLICE partials per column (in slice order), /512 ----
    float v[3];
    {
        const float inv = 1.0f / (float)SEQ;
        #pragma unroll
        for (int j = 0; j < 3; ++j) {
            const int col = tid + 256 * j;
            float s = 0.f;
            #pragma unroll
            for (int sl = 0; sl < NSLICE; ++sl)
                s += partial[(long)(b * NSLICE + sl) * EMBED + col];
            v[j] = s * inv;
        }
    }

    // ---- q_ball = map_to_ball(x_mean[b]) ----
    float ss = 0.f;
    #pragma unroll
    for (int j = 0; j < 3; ++j) ss += v[j] * v[j];
    ss = block_reduce_256(ss, red);
    const float scale1 = rsqrtf(fmaxf(ss, 1e-12f)) * 0.1f;
    float su = 0.f;
    #pragma unroll
    for (int j = 0; j < 3; ++j) { v[j] *= scale1; su += v[j] * v[j]; }
    su = block_reduce_256(su, red);
    const float n = sqrtf(fmaxf(su, 1e-15f));
    const float f = tanhf(n) / n;
    float sb = 0.f;
    #pragma unroll
    for (int j = 0; j < 3; ++j) { v[j] *= f; sb += v[j] * v[j]; }
    sb = block_reduce_256(sb, red);
    const float n2 = sqrtf(fmaxf(sb, 1e-15f));
    const float g = (n2 > MAX_NORM_F) ? (MAX_NORM_F / n2) : 1.0f;
    const float x2 = sb * g * g;
    #pragma unroll
    for (int j = 0; j < 3; ++j) q[tid + 256 * j] = v[j] * g;
    __syncthreads();

    // ---- xy[p] = <q, key_ball[p]> : dual-key interleave per wave (hides L2 latency).
    //      Per-key FMA order identical to the single-key version (bitwise-stable xy). ----
    const int wave = tid >> 6, lane = tid & 63;
    {
        float qv[12];
        #pragma unroll
        for (int j = 0; j < 12; ++j) qv[j] = q[j * 64 + lane];   // same values/order as before
        for (int p = wave; p < POOL; p += 8) {
            const int p2 = p + 4;
            const bool has2 = (p2 < POOL);
            const float* __restrict__ kb1 = keyball + (long)p * EMBED;
            const float* __restrict__ kb2 = keyball + (long)(has2 ? p2 : p) * EMBED;
            float acc1 = 0.f, acc2 = 0.f;
            #pragma unroll
            for (int j = 0; j < 12; ++j) {
                acc1 += qv[j] * kb1[j * 64 + lane];
                acc2 += qv[j] * kb2[j * 64 + lane];
            }
            #pragma unroll
            for (int m = 32; m >= 1; m >>= 1) {
                acc1 += __shfl_xor(acc1, m, 64);
                acc2 += __shfl_xor(acc2, m, 64);
            }
            if (lane == 0) {
                xy[p] = acc1;
                if (has2) xy[p2] = acc2;
            }
        }
    }
    __syncthreads();

    // ---- distances (scalar-only mobius math) ----
    if (tid < POOL) {
        const float s = xy[tid];
        const float y2 = keyy2[tid];
        const float A = 1.0f - 2.0f * s + y2;       // coeff on -x in num
        const float B = 1.0f - x2;                  // coeff on  y in num
        const float num2 = A * A * x2 + B * B * y2 - 2.0f * A * B * s;
        const float den = fmaxf(1.0f - 2.0f * s + x2 * y2, 1e-15f);
        float nn = sqrtf(fmaxf(num2 / (den * den), 1e-15f));
        nn = fminf(fmaxf(nn, 0.0f), 1.0f - 1e-7f);
        const float dd = logf((1.0f + nn) / (1.0f - nn));   // 2*artanh(nn)
        dist[tid] = dd;
        out[OFF_SIM + (long)b * POOL + tid] = -dd;
    }
    __syncthreads();

    // ---- top-5: wave-parallel butterfly min-reduce on wave 0.
    //      Lexicographic (dist, index) compare == serial ascending strict-< scan.
    //      Final sort + sum + writes on tid 0 in sorted-index order (reduce_sim bitwise-identical). ----
    if (wave == 0) {
        float myd = (lane < POOL) ? dist[lane] : 1e30f;
        const int myi = lane;
        int sel[TOPK];
        #pragma unroll
        for (int k = 0; k < TOPK; ++k) {
            float bd = myd; int bi = myi;
            #pragma unroll
            for (int m = 32; m >= 1; m >>= 1) {
                const float od = __shfl_xor(bd, m, 64);
                const int   oi = __shfl_xor(bi, m, 64);
                if (od < bd || (od == bd && oi < bi)) { bd = od; bi = oi; }
            }
            sel[k] = bi;                 // uniform across lanes
            if (myi == bi) myd = 1e30f;  // remove winner
        }
        if (lane == 0) {
            #pragma unroll
            for (int i = 0; i < TOPK; ++i)
                for (int j2 = i + 1; j2 < TOPK; ++j2)
                    if (sel[j2] < sel[i]) { int t = sel[i]; sel[i] = sel[j2]; sel[j2] = t; }
            float sum = 0.f;
            for (int k = 0; k < TOPK; ++k) {
                sum += dist[sel[k]];     // same (sorted-index) accumulation order as before
                out[OFF_IDX + (long)b * TOPK + k] = (float)sel[k];
                selw[b * TOPK + k] = sel[k];
            }
            atomicAdd(&out[OFF_RS], sum * (1.0f / 128.0f));
        }
    }
}

// Gather: one 768-float row per block.
// grid (30, 128): r in [0,25) -> prompt row copy (float4); r in [25,30) -> selected_key row (scalar,
// OFF_SK is not 16B-aligned).  block 192.
__global__ __launch_bounds__(192) void gather_kernel(
        const float* __restrict__ prompt, const float* __restrict__ keyball,
        const int* __restrict__ selw, float* __restrict__ out) {
    const int r = blockIdx.x, b = blockIdx.y, tid = threadIdx.x;
    if (r < TOPK * LEN) {
        const int k = r / LEN, l = r - k * LEN;
        const int pi = selw[b * TOPK + k];          // block-uniform -> scalar load
        const float4* __restrict__ src = (const float4*)prompt + ((long)pi * LEN + l) * EMBED4;
        float4* __restrict__ dst = (float4*)out + ((long)b * OUTROWS + r) * EMBED4;
        dst[tid] = src[tid];
    } else {
        const int k = r - TOPK * LEN;
        const int pi = selw[b * TOPK + k];
        const float* __restrict__ src = keyball + (long)pi * EMBED;
        float* __restrict__ dst = out + OFF_SK + ((long)b * TOPK + k) * EMBED;
        #pragma unroll
        for (int j = 0; j < 4; ++j) dst[tid + 192 * j] = src[tid + 192 * j];
    }
}

extern "C" void kernel_launch(void* const* d_in, const int* in_sizes, int n_in,
                              void* d_out, int out_size, void* d_ws, size_t ws_size,
                              hipStream_t stream) {
    const float* x      = (const float*)d_in[0];   // [128,512,768]
    const float* prompt = (const float*)d_in[1];   // [60,5,768]
    const float* pkey   = (const float*)d_in[2];   // [60,768]
    float* out = (float*)d_out;
    float* ws  = (float*)d_ws;

    float* partial = ws + WS_PARTIAL;
    float* keyball = ws + WS_KEYBALL;
    float* keyy2   = ws + WS_KEYY2;
    int*   selw    = (int*)(ws + WS_SEL);

    hipLaunchKernelGGL(mean_partial_copy, dim3(NSLICE, 128), dim3(192), 0, stream, x, out, partial);
    hipLaunchKernelGGL(keyball_kernel,    dim3(60),          dim3(256), 0, stream, pkey, keyball, keyy2);
    hipLaunchKernelGGL(topk_core,         dim3(128),         dim3(256), 0, stream,
                       partial, keyball, keyy2, out, selw);
    hipLaunchKernelGGL(gather_kernel,     dim3(30, 128),     dim3(192), 0, stream,
                       prompt, keyball, selw, out);
}

// Round 5
// 362.068 us; speedup vs baseline: 1.0918x; 1.0028x over previous
//
#include <hip/hip_runtime.h>

#define EMBED   768
#define EMBED4  192
#define POOL    60
#define BATCH   128
#define SEQ     512
#define TOPK    5
#define LEN     5
#define OUTROWS 537   // TOPK*LEN + SEQ = 25 + 512
#define NSLICE  16    // slices per batch in the streaming kernel

// ---- output layout (float offsets, concatenated in reference return order) ----
#define SZ_PE   (128L*537L*768L)          // 52,789,248
#define OFF_RS  (SZ_PE)                   // reduce_sim scalar
#define OFF_IDX (OFF_RS + 1)              // 128*5 = 640
#define OFF_SIM (OFF_IDX + 640)           // 128*60 = 7680
#define OFF_SK  (OFF_SIM + 7680)          // 128*5*768 = 491,520  (NOT 16B-aligned: OFF_SK%4==1)

// ---- workspace layout (float offsets) ----
#define WS_PARTIAL 0                      // 128*16*768 = 1,572,864
#define WS_KEYBALL 1572864                // 60*768     =    46,080
#define WS_KEYY2   1618944                // 60
#define WS_SEL     1619008                // 128*5 ints

#define MAX_NORM_F 0.996f                 // 1.0 - 4e-3

// native vector type for nontemporal builtins (HIP float4 is a struct and is rejected)
typedef float fx4 __attribute__((ext_vector_type(4)));

__device__ __forceinline__ float block_reduce_256(float v, float* red) {
    int tid = threadIdx.x;
    #pragma unroll
    for (int m = 32; m >= 1; m >>= 1) v += __shfl_xor(v, m, 64);
    if ((tid & 63) == 0) red[tid >> 6] = v;
    __syncthreads();
    float total = red[0] + red[1] + red[2] + red[3];
    __syncthreads();   // guard before red[] reuse
    return total;
}

// Fused: stream x_embed -> output rows [25..536] while accumulating per-batch partial sums.
// grid (NSLICE, 128 batches), block 192 (one float4 column per thread), 32 rows per block.
// 16-deep load batching: 16 loads in flight per thread before the dependent store pass
// (64 data VGPRs; ~90 total -> occupancy unaffected).  NT hints: stream is written/read once.
__global__ __launch_bounds__(192) void mean_partial_copy(
        const float* __restrict__ x, float* __restrict__ out, float* __restrict__ partial) {
    const int slice = blockIdx.x, b = blockIdx.y, tid = threadIdx.x;
    const fx4* __restrict__ x4 = (const fx4*)x;
    fx4* __restrict__ out4 = (fx4*)out;
    fx4* __restrict__ p4 = (fx4*)partial;

    if (slice == 0 && b == 0 && tid == 0) out[OFF_RS] = 0.0f;  // zero reduce_sim (pre-topk, stream-ordered)

    fx4 acc = (fx4)(0.f);
    const int rows = SEQ / NSLICE;  // 32
    const long ibase = ((long)b * SEQ + slice * rows) * EMBED4 + tid;
    const long obase = ((long)b * OUTROWS + 25 + slice * rows) * EMBED4 + tid;
    #pragma unroll
    for (int s0 = 0; s0 < rows; s0 += 16) {
        fx4 v[16];
        #pragma unroll
        for (int i = 0; i < 16; ++i)
            v[i] = __builtin_nontemporal_load(&x4[ibase + (long)(s0 + i) * EMBED4]);
        #pragma unroll
        for (int i = 0; i < 16; ++i) {
            // accumulate in the same s = 0..31 order as before (bitwise-identical mean)
            acc += v[i];
            __builtin_nontemporal_store(v[i], &out4[obase + (long)(s0 + i) * EMBED4]);
        }
    }
    p4[(long)(b * NSLICE + slice) * EMBED4 + tid] = acc;   // read soon by topk_core -> keep cached
}

// map_to_ball(prompt_key) -> keyball, keyy2.  grid 60, block 256 (3 elems/thread)
__global__ __launch_bounds__(256) void keyball_kernel(
        const float* __restrict__ pkey, float* __restrict__ keyball, float* __restrict__ keyy2) {
    __shared__ float red[4];
    const int p = blockIdx.x, tid = threadIdx.x;
    float v[3];
    float ss = 0.f;
    #pragma unroll
    for (int j = 0; j < 3; ++j) { v[j] = pkey[p * EMBED + tid + 256 * j]; ss += v[j] * v[j]; }
    ss = block_reduce_256(ss, red);
    const float scale1 = rsqrtf(fmaxf(ss, 1e-12f)) * 0.1f;   // l2_normalize * MAP_SCALE
    float su = 0.f;
    #pragma unroll
    for (int j = 0; j < 3; ++j) { v[j] *= scale1; su += v[j] * v[j]; }
    su = block_reduce_256(su, red);
    const float n = sqrtf(fmaxf(su, 1e-15f));
    const float f = tanhf(n) / n;                             // expmap0
    float sb = 0.f;
    #pragma unroll
    for (int j = 0; j < 3; ++j) { v[j] *= f; sb += v[j] * v[j]; }
    sb = block_reduce_256(sb, red);
    const float n2 = sqrtf(fmaxf(sb, 1e-15f));
    const float g = (n2 > MAX_NORM_F) ? (MAX_NORM_F / n2) : 1.0f;  // proju0
    #pragma unroll
    for (int j = 0; j < 3; ++j) keyball[p * EMBED + tid + 256 * j] = v[j] * g;
    if (tid == 0) keyy2[p] = sb * g * g;
}

// Per-batch: finalize mean, q_ball, distances, similarity, top-5, idx, reduce_sim.
// grid 128, block 256.  Latency-oriented: 4-way key interleave in the xy phase,
// wave-parallel top-5 with exact (dist,index) tie-break semantics.
__global__ __launch_bounds__(256) void topk_core(
        const float* __restrict__ partial, const float* __restrict__ keyball,
        const float* __restrict__ keyy2, float* __restrict__ out, int* __restrict__ selw) {
    __shared__ float red[4];
    __shared__ float q[EMBED];
    __shared__ float xy[POOL];
    __shared__ float dist[POOL];
    const int b = blockIdx.x, tid = threadIdx.x;

    // ---- finalize mean: sum NSLICE partials per column (in slice order), /512 ----
    float v[3];
    {
        const float inv = 1.0f / (float)SEQ;
        #pragma unroll
        for (int j = 0; j < 3; ++j) {
            const int col = tid + 256 * j;
            float s = 0.f;
            #pragma unroll
            for (int sl = 0; sl < NSLICE; ++sl)
                s += partial[(long)(b * NSLICE + sl) * EMBED + col];
            v[j] = s * inv;
        }
    }

    // ---- q_ball = map_to_ball(x_mean[b]) ----
    float ss = 0.f;
    #pragma unroll
    for (int j = 0; j < 3; ++j) ss += v[j] * v[j];
    ss = block_reduce_256(ss, red);
    const float scale1 = rsqrtf(fmaxf(ss, 1e-12f)) * 0.1f;
    float su = 0.f;
    #pragma unroll
    for (int j = 0; j < 3; ++j) { v[j] *= scale1; su += v[j] * v[j]; }
    su = block_reduce_256(su, red);
    const float n = sqrtf(fmaxf(su, 1e-15f));
    const float f = tanhf(n) / n;
    float sb = 0.f;
    #pragma unroll
    for (int j = 0; j < 3; ++j) { v[j] *= f; sb += v[j] * v[j]; }
    sb = block_reduce_256(sb, red);
    const float n2 = sqrtf(fmaxf(sb, 1e-15f));
    const float g = (n2 > MAX_NORM_F) ? (MAX_NORM_F / n2) : 1.0f;
    const float x2 = sb * g * g;
    #pragma unroll
    for (int j = 0; j < 3; ++j) q[tid + 256 * j] = v[j] * g;
    __syncthreads();

    // ---- xy[p] = <q, key_ball[p]> : 4-way key interleave per wave (hides L2 latency).
    //      Per-key FMA order identical to the single-key version (bitwise-stable xy).
    //      Wave w owns keys {w, w+4, ..., w+56}; iter p0 covers p0, p0+4, p0+8, p0+12.
    //      p0+4 and p0+8 are always < POOL for this schedule; only p0+12 needs a guard. ----
    const int wave = tid >> 6, lane = tid & 63;
    {
        float qv[12];
        #pragma unroll
        for (int j = 0; j < 12; ++j) qv[j] = q[j * 64 + lane];   // same values/order as before
        for (int p0 = wave; p0 < POOL; p0 += 16) {
            const bool h3 = (p0 + 12) < POOL;
            const float* __restrict__ kb0 = keyball + (long)p0 * EMBED;
            const float* __restrict__ kb1 = keyball + (long)(p0 + 4) * EMBED;
            const float* __restrict__ kb2 = keyball + (long)(p0 + 8) * EMBED;
            const float* __restrict__ kb3 = keyball + (long)(h3 ? p0 + 12 : p0) * EMBED;
            float a0 = 0.f, a1 = 0.f, a2 = 0.f, a3 = 0.f;
            #pragma unroll
            for (int j = 0; j < 12; ++j) {
                const float qj = qv[j];
                a0 += qj * kb0[j * 64 + lane];
                a1 += qj * kb1[j * 64 + lane];
                a2 += qj * kb2[j * 64 + lane];
                a3 += qj * kb3[j * 64 + lane];
            }
            #pragma unroll
            for (int m = 32; m >= 1; m >>= 1) {
                a0 += __shfl_xor(a0, m, 64);
                a1 += __shfl_xor(a1, m, 64);
                a2 += __shfl_xor(a2, m, 64);
                a3 += __shfl_xor(a3, m, 64);
            }
            if (lane == 0) {
                xy[p0]      = a0;
                xy[p0 + 4]  = a1;
                xy[p0 + 8]  = a2;
                if (h3) xy[p0 + 12] = a3;
            }
        }
    }
    __syncthreads();

    // ---- distances (scalar-only mobius math) ----
    if (tid < POOL) {
        const float s = xy[tid];
        const float y2 = keyy2[tid];
        const float A = 1.0f - 2.0f * s + y2;       // coeff on -x in num
        const float B = 1.0f - x2;                  // coeff on  y in num
        const float num2 = A * A * x2 + B * B * y2 - 2.0f * A * B * s;
        const float den = fmaxf(1.0f - 2.0f * s + x2 * y2, 1e-15f);
        float nn = sqrtf(fmaxf(num2 / (den * den), 1e-15f));
        nn = fminf(fmaxf(nn, 0.0f), 1.0f - 1e-7f);
        const float dd = logf((1.0f + nn) / (1.0f - nn));   // 2*artanh(nn)
        dist[tid] = dd;
        out[OFF_SIM + (long)b * POOL + tid] = -dd;
    }
    __syncthreads();

    // ---- top-5: wave-parallel butterfly min-reduce on wave 0.
    //      Lexicographic (dist, index) compare == serial ascending strict-< scan.
    //      Final sort + sum + writes on tid 0 in sorted-index order (reduce_sim bitwise-identical). ----
    if (wave == 0) {
        float myd = (lane < POOL) ? dist[lane] : 1e30f;
        const int myi = lane;
        int sel[TOPK];
        #pragma unroll
        for (int k = 0; k < TOPK; ++k) {
            float bd = myd; int bi = myi;
            #pragma unroll
            for (int m = 32; m >= 1; m >>= 1) {
                const float od = __shfl_xor(bd, m, 64);
                const int   oi = __shfl_xor(bi, m, 64);
                if (od < bd || (od == bd && oi < bi)) { bd = od; bi = oi; }
            }
            sel[k] = bi;                 // uniform across lanes
            if (myi == bi) myd = 1e30f;  // remove winner
        }
        if (lane == 0) {
            #pragma unroll
            for (int i = 0; i < TOPK; ++i)
                for (int j2 = i + 1; j2 < TOPK; ++j2)
                    if (sel[j2] < sel[i]) { int t = sel[i]; sel[i] = sel[j2]; sel[j2] = t; }
            float sum = 0.f;
            for (int k = 0; k < TOPK; ++k) {
                sum += dist[sel[k]];     // same (sorted-index) accumulation order as before
                out[OFF_IDX + (long)b * TOPK + k] = (float)sel[k];
                selw[b * TOPK + k] = sel[k];
            }
            atomicAdd(&out[OFF_RS], sum * (1.0f / 128.0f));
        }
    }
}

// Gather: one 768-float row per block.
// grid (30, 128): r in [0,25) -> prompt row copy (float4, NT store: write-once);
// r in [25,30) -> selected_key row (scalar, OFF_SK is not 16B-aligned).  block 192.
// Reads (prompt/keyball) stay cached: reused across the 128 batches (L2/L3-hot).
__global__ __launch_bounds__(192) void gather_kernel(
        const float* __restrict__ prompt, const float* __restrict__ keyball,
        const int* __restrict__ selw, float* __restrict__ out) {
    const int r = blockIdx.x, b = blockIdx.y, tid = threadIdx.x;
    if (r < TOPK * LEN) {
        const int k = r / LEN, l = r - k * LEN;
        const int pi = selw[b * TOPK + k];          // block-uniform -> scalar load
        const fx4* __restrict__ src = (const fx4*)prompt + ((long)pi * LEN + l) * EMBED4;
        fx4* __restrict__ dst = (fx4*)out + ((long)b * OUTROWS + r) * EMBED4;
        __builtin_nontemporal_store(src[tid], &dst[tid]);
    } else {
        const int k = r - TOPK * LEN;
        const int pi = selw[b * TOPK + k];
        const float* __restrict__ src = keyball + (long)pi * EMBED;
        float* __restrict__ dst = out + OFF_SK + ((long)b * TOPK + k) * EMBED;
        #pragma unroll
        for (int j = 0; j < 4; ++j)
            __builtin_nontemporal_store(src[tid + 192 * j], &dst[tid + 192 * j]);
    }
}

extern "C" void kernel_launch(void* const* d_in, const int* in_sizes, int n_in,
                              void* d_out, int out_size, void* d_ws, size_t ws_size,
                              hipStream_t stream) {
    const float* x      = (const float*)d_in[0];   // [128,512,768]
    const float* prompt = (const float*)d_in[1];   // [60,5,768]
    const float* pkey   = (const float*)d_in[2];   // [60,768]
    float* out = (float*)d_out;
    float* ws  = (float*)d_ws;

    float* partial = ws + WS_PARTIAL;
    float* keyball = ws + WS_KEYBALL;
    float* keyy2   = ws + WS_KEYY2;
    int*   selw    = (int*)(ws + WS_SEL);

    hipLaunchKernelGGL(mean_partial_copy, dim3(NSLICE, 128), dim3(192), 0, stream, x, out, partial);
    hipLaunchKernelGGL(keyball_kernel,    dim3(60),          dim3(256), 0, stream, pkey, keyball, keyy2);
    hipLaunchKernelGGL(topk_core,         dim3(128),         dim3(256), 0, stream,
                       partial, keyball, keyy2, out, selw);
    hipLaunchKernelGGL(gather_kernel,     dim3(30, 128),     dim3(192), 0, stream,
                       prompt, keyball, selw, out);
}